// Round 1
// 168.584 us; speedup vs baseline: 1.0867x; 1.0867x over previous
//
#include <hip/hip_runtime.h>

typedef _Float16 half2v __attribute__((ext_vector_type(2)));
typedef _Float16 half4v __attribute__((ext_vector_type(4)));
typedef _Float16 half8v __attribute__((ext_vector_type(8)));
typedef float   float4v __attribute__((ext_vector_type(4)));

#define INC     16
#define OUTC    16
#define EFN     13
#define HIDC    32
#define EPB     512    // edges per block
#define NTILES  (EPB / 16)
#define MAXSPAN 80     // max node-range per block (avg span ~32; >9-sigma safe)

#define GLOBAL_AS __attribute__((address_space(1)))
#define LDS_AS    __attribute__((address_space(3)))

union H8 { half8v v; half2v h2[4]; };

#define SB(t, l, j) (((t) * 64 + (l)) * 8 + (j))

// ---------------------------------------------------------------------------
// One-time: pack W2 into the f16 B-fragment image (linear in SB order) with
// the k-permutation kappa(q,j) = (j<4) ? q*4+j : 16+q*4+(j&3), matching the
// h-slices each lane holds after the two 16x16x16 W1 MFMAs.
// ---------------------------------------------------------------------------
__global__ __launch_bounds__(256) void pack_w2(const float* __restrict__ W2,
                                               _Float16* __restrict__ wsB)
{
    const int i = blockIdx.x * 256 + threadIdx.x;   // 0..8191 half index
    const int j = i & 7;
    const int l = (i >> 3) & 63;
    const int t = i >> 9;
    const int q = l >> 4, n = l & 15;
    const int kk = (j < 4) ? (q * 4 + j) : (16 + q * 4 + (j & 3));
    wsB[i] = (_Float16)W2[kk * 256 + t * 16 + n];
}

// ---------------------------------------------------------------------------
// MFMA edge kernel, atomic-free across blocks.
//   h(32x16 per tile) via 2 x mfma_16x16x16_f16 (B = staged f16 edgefeats).
//   prod(E x 16) = Z(E x 512) @ W2r + sel @ b2r via 17 x mfma_16x16x32_f16,
//   B-fragments async-loaded from the prebuilt global image (global_load_lds).
//   Sorted idxd => per-block LDS bins; interior nodes get deg-division fused;
//   boundary runs land in per-block ws slots for the fixup kernel.
// ---------------------------------------------------------------------------
__global__ __launch_bounds__(256) void edge_kernel(
    const float* __restrict__ x,          // (N,16)
    const float* __restrict__ edgefeats,  // (E,13)
    const float* __restrict__ W1,         // (13,32)
    const float* __restrict__ b1,         // (32,)
    const float* __restrict__ b2,         // (256,)
    const int*   __restrict__ idxn,       // (E,)
    const int*   __restrict__ idxd,       // (E,) sorted
    const float* __restrict__ degs,       // (N,)
    const _Float16* __restrict__ wsB,     // (8192,) prebuilt B image
    float*       __restrict__ out,        // (N,16) final output
    float*       __restrict__ wsPfirst,   // (nblocks,16)
    float*       __restrict__ wsPlast,    // (nblocks,16)
    int*         __restrict__ wsMeta,     // (nblocks,4)
    int E)
{
    __shared__ __align__(16) _Float16 sB[16 * 64 * 8];   // 16 KB W2 frag image
    __shared__ __align__(16) _Float16 sEF[EPB * 16];     // 16 KB f16 edgefeats (13 + 3 pad)
    __shared__ float         lacc[MAXSPAN * OUTC];       // 5 KB
    __shared__ int           sidxn[EPB];                 // 2 KB
    __shared__ __align__(4) unsigned char su[EPB];       // 512 B

    const int tid  = threadIdx.x;
    const int lane = tid & 63;
    const int wid  = tid >> 6;
    const int n    = lane & 15;
    const int q    = lane >> 4;

    const long b0   = (long)blockIdx.x * EPB;
    const long bEnd = (b0 + EPB < (long)E) ? (b0 + EPB) : (long)E;
    const int  d_lo = idxd[b0];
    const int  d_hi = idxd[bEnd - 1];
    const int  span = d_hi - d_lo;   // < MAXSPAN by construction

    // ---- async: pull prebuilt W2 fragment image into LDS (linear, no VALU) ----
    #pragma unroll
    for (int it = 0; it < 4; ++it) {
        const int chunk = wid + it * 4;                 // 16 chunks x 1 KB
        __builtin_amdgcn_global_load_lds(
            (const GLOBAL_AS unsigned int*)((const char*)wsB + chunk * 1024 + lane * 16),
            (LDS_AS unsigned int*)((char*)sB + chunk * 1024),
            16, 0, 0);
    }

    // ---- stage edgefeats -> f16 LDS rows of 16 (coalesced float4 reads) ----
    for (int r = tid; r < EPB; r += 256) {              // zero pad cols 13..15
        sEF[r * 16 + 13] = (_Float16)0.f;
        *(unsigned*)&sEF[r * 16 + 14] = 0u;
    }
    {
        const long etot   = (long)E * EFN;
        const long base4  = (long)blockIdx.x * (EPB * EFN / 4);
        for (int i4 = tid; i4 < EPB * EFN / 4; i4 += 256) {   // 1664 float4s
            const long ge0 = (base4 + i4) * 4;
            float4 v;
            if (ge0 + 3 < etot) {
                v = ((const float4*)edgefeats)[base4 + i4];
            } else {                                     // tail: per-element clamp
                float* vp = &v.x;
                #pragma unroll
                for (int u = 0; u < 4; ++u) {
                    long gi = ge0 + u;
                    if (gi >= etot) gi = etot - 1;
                    vp[u] = edgefeats[gi];
                }
            }
            const float* vp = &v.x;
            #pragma unroll
            for (int u = 0; u < 4; ++u) {
                const int i = i4 * 4 + u;
                const int e = i / 13;
                const int f = i - e * 13;
                sEF[e * 16 + f] = (_Float16)vp[u];
            }
        }
    }

    // ---- zero bins, stage idxn + idxd-offset bytes ----
    #pragma unroll
    for (int it = 0; it < MAXSPAN * OUTC / 256; ++it) lacc[tid + it * 256] = 0.0f;
    {
        const int i2 = tid * 2;
        long e0 = b0 + i2, e1 = b0 + i2 + 1;
        if (e0 >= (long)E) e0 = E - 1;
        if (e1 >= (long)E) e1 = E - 1;
        sidxn[i2]     = idxn[e0];
        sidxn[i2 + 1] = idxn[e1];
        const unsigned u0 = (unsigned)(idxd[e0] - d_lo);
        const unsigned u1 = (unsigned)(idxd[e1] - d_lo);
        *(unsigned short*)&su[i2] = (unsigned short)(u0 | (u1 << 8));
    }

    // ---- per-lane constants: W1^T A-fragments, b1 C-init, b2 B-fragment ----
    half4v a1, a2;
    float4v c1, c2;
    #pragma unroll
    for (int jj = 0; jj < 4; ++jj) {
        const int f = q * 4 + jj;
        const bool ok = (f < EFN);
        a1[jj] = ok ? (_Float16)W1[f * HIDC + n]      : (_Float16)0.f;
        a2[jj] = ok ? (_Float16)W1[f * HIDC + 16 + n] : (_Float16)0.f;
        c1[jj] = b1[q * 4 + jj];
        c2[jj] = b1[16 + q * 4 + jj];
    }
    half8v bfragB2;
    #pragma unroll
    for (int j = 0; j < 8; ++j) {
        _Float16 val = (_Float16)0.f;
        if (q < 2) val = (_Float16)b2[(q * 8 + j) * 16 + n];
        bfragB2[j] = val;
    }

    __syncthreads();   // drains global_load_lds (vmcnt) + LDS stores

    // ---- tile loop: 16 edges per wave-tile ----
    for (int t16 = wid; t16 < NTILES; t16 += 4) {
        const long base = b0 + (long)t16 * 16;
        const long eM   = base + n;
        const bool vM   = (eM < (long)E);

        const unsigned u4  = *(const unsigned*)&su[t16 * 16 + q * 4];
        const int      node = sidxn[t16 * 16 + n];

        // sel = x[node] (zero for pad edges)
        const float4* xp = (const float4*)(x + (size_t)node * INC);
        float4 s0 = xp[0], s1 = xp[1], s2 = xp[2], s3 = xp[3];
        if (!vM) { s0 = make_float4(0,0,0,0); s1 = s0; s2 = s0; s3 = s0; }

        half2v selh[8];
        { half2v t = {(_Float16)s0.x, (_Float16)s0.y}; selh[0] = t; }
        { half2v t = {(_Float16)s0.z, (_Float16)s0.w}; selh[1] = t; }
        { half2v t = {(_Float16)s1.x, (_Float16)s1.y}; selh[2] = t; }
        { half2v t = {(_Float16)s1.z, (_Float16)s1.w}; selh[3] = t; }
        { half2v t = {(_Float16)s2.x, (_Float16)s2.y}; selh[4] = t; }
        { half2v t = {(_Float16)s2.z, (_Float16)s2.w}; selh[5] = t; }
        { half2v t = {(_Float16)s3.x, (_Float16)s3.y}; selh[6] = t; }
        { half2v t = {(_Float16)s3.z, (_Float16)s3.w}; selh[7] = t; }

        // h^T = relu(W1^T @ EF^T + b1): lane holds hids {q*4+r, 16+q*4+r}
        const half4v efB = *(const half4v*)&sEF[(t16 * 16 + n) * 16 + q * 4];
        const float4v hf1 = __builtin_amdgcn_mfma_f32_16x16x16f16(a1, efB, c1, 0, 0, 0);
        const float4v hf2 = __builtin_amdgcn_mfma_f32_16x16x16f16(a2, efB, c2, 0, 0, 0);

        H8 hu;   // hu half j <-> hid kappa(q,j); matches pack_w2's sB image
        #pragma unroll
        for (int r = 0; r < 2; ++r) {
            half2v t1 = {(_Float16)fmaxf(hf1[2*r], 0.f), (_Float16)fmaxf(hf1[2*r+1], 0.f)};
            half2v t2 = {(_Float16)fmaxf(hf2[2*r], 0.f), (_Float16)fmaxf(hf2[2*r+1], 0.f)};
            hu.h2[r]     = t1;
            hu.h2[2 + r] = t2;
        }

        // ---- 16 W2 steps (B from LDS) + 1 b2 step ----
        float4v acc = {0.f, 0.f, 0.f, 0.f};
        #pragma unroll
        for (int t = 0; t < 16; ++t) {
            _Float16 sv = (t & 1) ? selh[t >> 1][1] : selh[t >> 1][0];
            half2v sb = {sv, sv};
            H8 a;
            a.h2[0] = sb * hu.h2[0];
            a.h2[1] = sb * hu.h2[1];
            a.h2[2] = sb * hu.h2[2];
            a.h2[3] = sb * hu.h2[3];
            const half8v bf = *(const half8v*)&sB[SB(t, lane, 0)];
            acc = __builtin_amdgcn_mfma_f32_16x16x32_f16(a.v, bf, acc, 0, 0, 0);
        }
        {
            H8 a;
            #pragma unroll
            for (int j2 = 0; j2 < 4; ++j2) {
                half2v zz = {(_Float16)0.f, (_Float16)0.f};
                a.h2[j2] = (q < 2) ? selh[q * 4 + j2] : zz;
            }
            acc = __builtin_amdgcn_mfma_f32_16x16x32_f16(a.v, bfragB2, acc, 0, 0, 0);
        }

        // ---- scatter into LDS bins; combine when the 4-edge run is one node
        const unsigned rep = (u4 & 0xffu) * 0x01010101u;
        if (u4 == rep) {
            atomicAdd(&lacc[(u4 & 0xffu) * OUTC + n],
                      acc[0] + acc[1] + acc[2] + acc[3]);
        } else {
            #pragma unroll
            for (int r = 0; r < 4; ++r)
                atomicAdd(&lacc[((u4 >> (8 * r)) & 0xffu) * OUTC + n], acc[r]);
        }
    }

    __syncthreads();

    // ---- flush: fuse deg-division for complete segments -> out;
    //      boundary partials -> ws slots (no global atomics anywhere) ----
    const bool first_starts = (b0 == 0)        || (idxd[b0 - 1] != d_lo);
    const bool last_ends    = (bEnd == (long)E) || (idxd[bEnd]   != d_hi);

    for (int i = tid; i < (span + 1) * OUTC; i += 256) {
        const int u = i >> 4;
        const int o = i & 15;
        const int v = d_lo + u;
        const float bin = lacc[u * OUTC + o];
        const bool starts = (u > 0)    || first_starts;
        const bool ends   = (u < span) || last_ends;
        if (starts && ends) {
            const float dg = degs[v];
            out[(size_t)v * OUTC + o] = (dg > 0.0f) ? bin / dg : 0.0f;
        } else if (!starts) {
            wsPfirst[(size_t)blockIdx.x * OUTC + o] = bin;
        } else {
            wsPlast[(size_t)blockIdx.x * OUTC + o] = bin;
        }
    }
    if (tid == 0) {
        wsMeta[blockIdx.x * 4 + 0] = d_hi;
        wsMeta[blockIdx.x * 4 + 1] = last_ends ? 1 : 0;
        wsMeta[blockIdx.x * 4 + 2] =
            (((span > 0) || first_starts) && !last_ends) ? 1 : 0;
    }
}

// ---------------------------------------------------------------------------
// Fixup: (a) owner blocks walk their open run across following blocks and
// write the finalized node; (b) deg-0 nodes get zeros.
// ---------------------------------------------------------------------------
__global__ __launch_bounds__(256) void fixup_kernel(
    const float* __restrict__ degs,
    float*       __restrict__ out,
    const float* __restrict__ wsPfirst,
    const float* __restrict__ wsPlast,
    const int*   __restrict__ wsMeta,
    int N, int nblocks)
{
    const int t = blockIdx.x * 256 + threadIdx.x;

    if (t < nblocks && wsMeta[t * 4 + 2]) {
        const int v = wsMeta[t * 4 + 0];
        float tot[OUTC];
        #pragma unroll
        for (int o = 0; o < OUTC; ++o) tot[o] = wsPlast[(size_t)t * OUTC + o];
        for (int j = t + 1; j < nblocks; ++j) {
            #pragma unroll
            for (int o = 0; o < OUTC; ++o) tot[o] += wsPfirst[(size_t)j * OUTC + o];
            if (wsMeta[j * 4 + 0] != v || wsMeta[j * 4 + 1]) break;
        }
        const float dg = degs[v];   // v has edges => dg > 0
        #pragma unroll
        for (int o = 0; o < OUTC; ++o) out[(size_t)v * OUTC + o] = tot[o] / dg;
    }

    if (t < N && degs[t] == 0.0f) {
        float4* op = (float4*)(out + (size_t)t * OUTC);
        const float4 z = make_float4(0, 0, 0, 0);
        op[0] = z; op[1] = z; op[2] = z; op[3] = z;
    }
}

// ---------------------------------------------------------------------------
extern "C" void kernel_launch(void* const* d_in, const int* in_sizes, int n_in,
                              void* d_out, int out_size, void* d_ws, size_t ws_size,
                              hipStream_t stream)
{
    const float* x         = (const float*)d_in[0];
    const float* edgefeats = (const float*)d_in[1];
    const float* W1        = (const float*)d_in[2];
    const float* b1        = (const float*)d_in[3];
    const float* W2        = (const float*)d_in[4];
    const float* b2        = (const float*)d_in[5];
    const int*   idxn      = (const int*)d_in[6];
    const int*   idxd      = (const int*)d_in[7];
    const float* degs      = (const float*)d_in[8];

    const int E = in_sizes[6];
    const int N = in_sizes[8];
    const int nblocks = (E + EPB - 1) / EPB;

    _Float16* wsB    = (_Float16*)d_ws;                       // 16 KB image
    float* wsPfirst  = (float*)((char*)d_ws + 16384);
    float* wsPlast   = wsPfirst + (size_t)nblocks * OUTC;
    int*   wsMeta    = (int*)(wsPlast + (size_t)nblocks * OUTC);

    pack_w2<<<32, 256, 0, stream>>>(W2, wsB);

    edge_kernel<<<nblocks, 256, 0, stream>>>(x, edgefeats, W1, b1, b2,
                                             idxn, idxd, degs, wsB, (float*)d_out,
                                             wsPfirst, wsPlast, wsMeta, E);

    const int fthreads = (N > nblocks) ? N : nblocks;
    fixup_kernel<<<(fthreads + 255) / 256, 256, 0, stream>>>(
        degs, (float*)d_out, wsPfirst, wsPlast, wsMeta, N, nblocks);
}

// Round 2
// 161.299 us; speedup vs baseline: 1.1358x; 1.0452x over previous
//
#include <hip/hip_runtime.h>

typedef _Float16 half2v __attribute__((ext_vector_type(2)));
typedef _Float16 half4v __attribute__((ext_vector_type(4)));
typedef _Float16 half8v __attribute__((ext_vector_type(8)));
typedef float   float4v __attribute__((ext_vector_type(4)));

#define INC     16
#define OUTC    16
#define EFN     13
#define HIDC    32
#define EPB     512    // edges per block
#define NTILES  (EPB / 16)
#define MAXSPAN 80     // max node-range per block (avg span ~32; >9-sigma safe)

#define GLOBAL_AS __attribute__((address_space(1)))
#define LDS_AS    __attribute__((address_space(3)))

union H8 { half8v v; half2v h2[4]; };

#define SB(t, l, j) (((t) * 64 + (l)) * 8 + (j))

// ---------------------------------------------------------------------------
// One-time: pack W2 into the f16 B-fragment image (linear in SB order) with
// the k-permutation kappa(q,j) = (j<4) ? q*4+j : 16+q*4+(j&3), matching the
// h-slices each lane holds after the two 16x16x16 W1 MFMAs.
// ---------------------------------------------------------------------------
__global__ __launch_bounds__(256) void pack_w2(const float* __restrict__ W2,
                                               _Float16* __restrict__ wsB)
{
    const int i = blockIdx.x * 256 + threadIdx.x;   // 0..8191 half index
    const int j = i & 7;
    const int l = (i >> 3) & 63;
    const int t = i >> 9;
    const int q = l >> 4, n = l & 15;
    const int kk = (j < 4) ? (q * 4 + j) : (16 + q * 4 + (j & 3));
    wsB[i] = (_Float16)W2[kk * 256 + t * 16 + n];
}

// ---------------------------------------------------------------------------
// MFMA edge kernel, atomic-free across blocks, no edgefeat staging:
//   each lane pulls its 4-float W1-B-fragment straight from global (rows of
//   13 floats; q<3 -> offset q*4, q==3 -> offset 9, take .w), so LDS holds
//   only the 16 KB W2 image + bins => 23.75 KB => ~6 blocks/CU.
//   h(32x16 per tile) via 2 x mfma_16x16x16_f16;
//   prod = Z(E x 512) @ W2r + sel @ b2r via 17 x mfma_16x16x32_f16.
//   Sorted idxd => per-block LDS bins; interior nodes get deg-division fused;
//   boundary runs land in per-block ws slots for the fixup kernel.
// ---------------------------------------------------------------------------
__global__ __launch_bounds__(256) void edge_kernel(
    const float* __restrict__ x,          // (N,16)
    const float* __restrict__ edgefeats,  // (E,13)
    const float* __restrict__ W1,         // (13,32)
    const float* __restrict__ b1,         // (32,)
    const float* __restrict__ b2,         // (256,)
    const int*   __restrict__ idxn,       // (E,)
    const int*   __restrict__ idxd,       // (E,) sorted
    const float* __restrict__ degs,       // (N,)
    const _Float16* __restrict__ wsB,     // (8192,) prebuilt B image
    float*       __restrict__ out,        // (N,16) final output
    float*       __restrict__ wsPfirst,   // (nblocks,16)
    float*       __restrict__ wsPlast,    // (nblocks,16)
    int*         __restrict__ wsMeta,     // (nblocks,4)
    int E)
{
    __shared__ __align__(16) _Float16 sB[16 * 64 * 8];   // 16 KB W2 frag image
    __shared__ float         lacc[MAXSPAN * OUTC];       // 5 KB
    __shared__ int           sidxn[EPB];                 // 2 KB
    __shared__ __align__(4) unsigned char su[EPB];       // 512 B

    const int tid  = threadIdx.x;
    const int lane = tid & 63;
    const int wid  = tid >> 6;
    const int n    = lane & 15;
    const int q    = lane >> 4;

    const long b0   = (long)blockIdx.x * EPB;
    const long bEnd = (b0 + EPB < (long)E) ? (b0 + EPB) : (long)E;
    const int  d_lo = idxd[b0];
    const int  d_hi = idxd[bEnd - 1];
    const int  span = d_hi - d_lo;   // < MAXSPAN by construction

    // ---- async: pull prebuilt W2 fragment image into LDS (linear, no VALU) ----
    #pragma unroll
    for (int it = 0; it < 4; ++it) {
        const int chunk = wid + it * 4;                 // 16 chunks x 1 KB
        __builtin_amdgcn_global_load_lds(
            (const GLOBAL_AS unsigned int*)((const char*)wsB + chunk * 1024 + lane * 16),
            (LDS_AS unsigned int*)((char*)sB + chunk * 1024),
            16, 0, 0);
    }

    // ---- zero bins, stage idxn + idxd-offset bytes ----
    #pragma unroll
    for (int it = 0; it < MAXSPAN * OUTC / 256; ++it) lacc[tid + it * 256] = 0.0f;
    {
        const int i2 = tid * 2;
        long e0 = b0 + i2, e1 = b0 + i2 + 1;
        if (e0 >= (long)E) e0 = E - 1;
        if (e1 >= (long)E) e1 = E - 1;
        sidxn[i2]     = idxn[e0];
        sidxn[i2 + 1] = idxn[e1];
        const unsigned u0 = (unsigned)(idxd[e0] - d_lo);
        const unsigned u1 = (unsigned)(idxd[e1] - d_lo);
        *(unsigned short*)&su[i2] = (unsigned short)(u0 | (u1 << 8));
    }

    // ---- per-lane constants: W1^T A-fragments, b1 C-init, b2 B-fragment ----
    half4v a1, a2;
    float4v c1, c2;
    #pragma unroll
    for (int jj = 0; jj < 4; ++jj) {
        const int f = q * 4 + jj;
        const bool ok = (f < EFN);
        a1[jj] = ok ? (_Float16)W1[f * HIDC + n]      : (_Float16)0.f;
        a2[jj] = ok ? (_Float16)W1[f * HIDC + 16 + n] : (_Float16)0.f;
        c1[jj] = b1[q * 4 + jj];
        c2[jj] = b1[16 + q * 4 + jj];
    }
    half8v bfragB2;
    #pragma unroll
    for (int j = 0; j < 8; ++j) {
        _Float16 val = (_Float16)0.f;
        if (q < 2) val = (_Float16)b2[(q * 8 + j) * 16 + n];
        bfragB2[j] = val;
    }

    // per-lane constant for the direct edgefeat fragment load
    const int f0 = (q < 3) ? (q * 4) : 9;   // q==3: load feats 9..12, keep .w

    __syncthreads();   // drains global_load_lds (vmcnt) + LDS stores

    // ---- tile loop: 16 edges per wave-tile ----
    for (int t16 = wid; t16 < NTILES; t16 += 4) {
        const long base = b0 + (long)t16 * 16;
        const long eM   = base + n;
        const bool vM   = (eM < (long)E);
        const long eMc  = vM ? eM : (long)(E - 1);

        const unsigned u4  = *(const unsigned*)&su[t16 * 16 + q * 4];
        const int      node = sidxn[t16 * 16 + n];

        // W1 B-fragment straight from global: 4 contiguous floats of this
        // edge's 13-float row (dword-aligned load; in-bounds incl. last edge)
        const float4 ef4 = *(const float4*)(edgefeats + (size_t)eMc * EFN + f0);

        // sel = x[node] (zero for pad edges)
        const float4* xp = (const float4*)(x + (size_t)node * INC);
        float4 s0 = xp[0], s1 = xp[1], s2 = xp[2], s3 = xp[3];
        if (!vM) { s0 = make_float4(0,0,0,0); s1 = s0; s2 = s0; s3 = s0; }

        half2v selh[8];
        { half2v t = {(_Float16)s0.x, (_Float16)s0.y}; selh[0] = t; }
        { half2v t = {(_Float16)s0.z, (_Float16)s0.w}; selh[1] = t; }
        { half2v t = {(_Float16)s1.x, (_Float16)s1.y}; selh[2] = t; }
        { half2v t = {(_Float16)s1.z, (_Float16)s1.w}; selh[3] = t; }
        { half2v t = {(_Float16)s2.x, (_Float16)s2.y}; selh[4] = t; }
        { half2v t = {(_Float16)s2.z, (_Float16)s2.w}; selh[5] = t; }
        { half2v t = {(_Float16)s3.x, (_Float16)s3.y}; selh[6] = t; }
        { half2v t = {(_Float16)s3.z, (_Float16)s3.w}; selh[7] = t; }

        half4v efB;
        if (q < 3) {
            efB[0] = (_Float16)ef4.x; efB[1] = (_Float16)ef4.y;
            efB[2] = (_Float16)ef4.z; efB[3] = (_Float16)ef4.w;
        } else {
            efB[0] = (_Float16)ef4.w; efB[1] = (_Float16)0.f;
            efB[2] = (_Float16)0.f;   efB[3] = (_Float16)0.f;
        }

        // h^T = relu(W1^T @ EF^T + b1): lane holds hids {q*4+r, 16+q*4+r}
        const float4v hf1 = __builtin_amdgcn_mfma_f32_16x16x16f16(a1, efB, c1, 0, 0, 0);
        const float4v hf2 = __builtin_amdgcn_mfma_f32_16x16x16f16(a2, efB, c2, 0, 0, 0);

        H8 hu;   // hu half j <-> hid kappa(q,j); matches pack_w2's sB image
        #pragma unroll
        for (int r = 0; r < 2; ++r) {
            half2v t1 = {(_Float16)fmaxf(hf1[2*r], 0.f), (_Float16)fmaxf(hf1[2*r+1], 0.f)};
            half2v t2 = {(_Float16)fmaxf(hf2[2*r], 0.f), (_Float16)fmaxf(hf2[2*r+1], 0.f)};
            hu.h2[r]     = t1;
            hu.h2[2 + r] = t2;
        }

        // ---- 16 W2 steps (B from LDS) + 1 b2 step ----
        float4v acc = {0.f, 0.f, 0.f, 0.f};
        #pragma unroll
        for (int t = 0; t < 16; ++t) {
            _Float16 sv = (t & 1) ? selh[t >> 1][1] : selh[t >> 1][0];
            half2v sb = {sv, sv};
            H8 a;
            a.h2[0] = sb * hu.h2[0];
            a.h2[1] = sb * hu.h2[1];
            a.h2[2] = sb * hu.h2[2];
            a.h2[3] = sb * hu.h2[3];
            const half8v bf = *(const half8v*)&sB[SB(t, lane, 0)];
            acc = __builtin_amdgcn_mfma_f32_16x16x32_f16(a.v, bf, acc, 0, 0, 0);
        }
        {
            H8 a;
            #pragma unroll
            for (int j2 = 0; j2 < 4; ++j2) {
                half2v zz = {(_Float16)0.f, (_Float16)0.f};
                a.h2[j2] = (q < 2) ? selh[q * 4 + j2] : zz;
            }
            acc = __builtin_amdgcn_mfma_f32_16x16x32_f16(a.v, bfragB2, acc, 0, 0, 0);
        }

        // ---- scatter into LDS bins; combine when the 4-edge run is one node
        const unsigned rep = (u4 & 0xffu) * 0x01010101u;
        if (u4 == rep) {
            atomicAdd(&lacc[(u4 & 0xffu) * OUTC + n],
                      acc[0] + acc[1] + acc[2] + acc[3]);
        } else {
            #pragma unroll
            for (int r = 0; r < 4; ++r)
                atomicAdd(&lacc[((u4 >> (8 * r)) & 0xffu) * OUTC + n], acc[r]);
        }
    }

    __syncthreads();

    // ---- flush: fuse deg-division for complete segments -> out;
    //      boundary partials -> ws slots (no global atomics anywhere) ----
    const bool first_starts = (b0 == 0)        || (idxd[b0 - 1] != d_lo);
    const bool last_ends    = (bEnd == (long)E) || (idxd[bEnd]   != d_hi);

    for (int i = tid; i < (span + 1) * OUTC; i += 256) {
        const int u = i >> 4;
        const int o = i & 15;
        const int v = d_lo + u;
        const float bin = lacc[u * OUTC + o];
        const bool starts = (u > 0)    || first_starts;
        const bool ends   = (u < span) || last_ends;
        if (starts && ends) {
            const float dg = degs[v];
            out[(size_t)v * OUTC + o] = (dg > 0.0f) ? bin / dg : 0.0f;
        } else if (!starts) {
            wsPfirst[(size_t)blockIdx.x * OUTC + o] = bin;
        } else {
            wsPlast[(size_t)blockIdx.x * OUTC + o] = bin;
        }
    }
    if (tid == 0) {
        wsMeta[blockIdx.x * 4 + 0] = d_hi;
        wsMeta[blockIdx.x * 4 + 1] = last_ends ? 1 : 0;
        wsMeta[blockIdx.x * 4 + 2] =
            (((span > 0) || first_starts) && !last_ends) ? 1 : 0;
    }
}

// ---------------------------------------------------------------------------
// Fixup: (a) owner blocks walk their open run across following blocks and
// write the finalized node; (b) deg-0 nodes get zeros.
// ---------------------------------------------------------------------------
__global__ __launch_bounds__(256) void fixup_kernel(
    const float* __restrict__ degs,
    float*       __restrict__ out,
    const float* __restrict__ wsPfirst,
    const float* __restrict__ wsPlast,
    const int*   __restrict__ wsMeta,
    int N, int nblocks)
{
    const int t = blockIdx.x * 256 + threadIdx.x;

    if (t < nblocks && wsMeta[t * 4 + 2]) {
        const int v = wsMeta[t * 4 + 0];
        float tot[OUTC];
        #pragma unroll
        for (int o = 0; o < OUTC; ++o) tot[o] = wsPlast[(size_t)t * OUTC + o];
        for (int j = t + 1; j < nblocks; ++j) {
            #pragma unroll
            for (int o = 0; o < OUTC; ++o) tot[o] += wsPfirst[(size_t)j * OUTC + o];
            if (wsMeta[j * 4 + 0] != v || wsMeta[j * 4 + 1]) break;
        }
        const float dg = degs[v];   // v has edges => dg > 0
        #pragma unroll
        for (int o = 0; o < OUTC; ++o) out[(size_t)v * OUTC + o] = tot[o] / dg;
    }

    if (t < N && degs[t] == 0.0f) {
        float4* op = (float4*)(out + (size_t)t * OUTC);
        const float4 z = make_float4(0, 0, 0, 0);
        op[0] = z; op[1] = z; op[2] = z; op[3] = z;
    }
}

// ---------------------------------------------------------------------------
extern "C" void kernel_launch(void* const* d_in, const int* in_sizes, int n_in,
                              void* d_out, int out_size, void* d_ws, size_t ws_size,
                              hipStream_t stream)
{
    const float* x         = (const float*)d_in[0];
    const float* edgefeats = (const float*)d_in[1];
    const float* W1        = (const float*)d_in[2];
    const float* b1        = (const float*)d_in[3];
    const float* W2        = (const float*)d_in[4];
    const float* b2        = (const float*)d_in[5];
    const int*   idxn      = (const int*)d_in[6];
    const int*   idxd      = (const int*)d_in[7];
    const float* degs      = (const float*)d_in[8];

    const int E = in_sizes[6];
    const int N = in_sizes[8];
    const int nblocks = (E + EPB - 1) / EPB;

    _Float16* wsB    = (_Float16*)d_ws;                       // 16 KB image
    float* wsPfirst  = (float*)((char*)d_ws + 16384);
    float* wsPlast   = wsPfirst + (size_t)nblocks * OUTC;
    int*   wsMeta    = (int*)(wsPlast + (size_t)nblocks * OUTC);

    pack_w2<<<32, 256, 0, stream>>>(W2, wsB);

    edge_kernel<<<nblocks, 256, 0, stream>>>(x, edgefeats, W1, b1, b2,
                                             idxn, idxd, degs, wsB, (float*)d_out,
                                             wsPfirst, wsPlast, wsMeta, E);

    const int fthreads = (N > nblocks) ? N : nblocks;
    fixup_kernel<<<(fthreads + 255) / 256, 256, 0, stream>>>(
        degs, (float*)d_out, wsPfirst, wsPlast, wsMeta, N, nblocks);
}